// Round 2
// baseline (621.891 us; speedup 1.0000x reference)
//
#include <hip/hip_runtime.h>
#include <cstdint>

// Problem constants: B=4, C=64, H=W=128, N=H*W=16384, out feature dim 89.
#define NPTS 16384

__device__ __forceinline__ float wsum(float v){
#pragma unroll
  for(int o=32;o>0;o>>=1) v += __shfl_xor(v, o, 64);
  return v;
}

// Transpose one [64][16384] fp32 matrix per batch (blockIdx.y) into [16384][64].
// Used for latents [C][HW] -> [HW][C] and for qf_flat viewed as [64][16384] -> uft.
__global__ __launch_bounds__(256) void k_tr(const float* __restrict__ in,
                                            float* __restrict__ out){
  __shared__ float t[64][65];
  const int b  = blockIdx.y;
  const int p0 = blockIdx.x * 64;
  const float* src = in  + (size_t)b * (64 * 16384);
  float*       dst = out + (size_t)b * (64 * 16384);
  const int tx = threadIdx.x & 63, ty = threadIdx.x >> 6; // ty in 0..3
#pragma unroll
  for(int j=0;j<16;j++){ int r = ty + j*4; t[r][tx] = src[(size_t)r*16384 + p0 + tx]; }
  __syncthreads();
#pragma unroll
  for(int j=0;j<16;j++){ int pr = ty + j*4; dst[(size_t)(p0+pr)*64 + tx] = t[tx][pr]; }
}

// One wave per point: bilinear-sample latents (via transposed lat_t, coalesced),
// plus the cheap extras: image sample (out[64]) and positional encoding (out[65..88]).
__global__ __launch_bounds__(256) void k_sample(const float* __restrict__ lat_t,
                                                const float* __restrict__ coords,
                                                const float* __restrict__ image,
                                                float* __restrict__ qf,
                                                float* __restrict__ out){
  const int lane = threadIdx.x & 63;
  const int pidx = blockIdx.x * 4 + (threadIdx.x >> 6);
  const int b = pidx >> 14, n = pidx & 16383;
  // xy = flip(coords,-1): x = coords[...,1], y = coords[...,0]
  const float y = coords[(size_t)pidx*2 + 0];
  const float x = coords[(size_t)pidx*2 + 1];

  // ---- latents grid (128x128), zeros padding ----
  float ix = ((x + 1.f)*128.f - 1.f)*0.5f;
  float iy = ((y + 1.f)*128.f - 1.f)*0.5f;
  float x0 = floorf(ix), y0 = floorf(iy);
  float wx1 = ix - x0, wy1 = iy - y0;
  float acc = 0.f, qcy = 0.f, qcx = 0.f;
  const float* latb = lat_t + (size_t)b*16384*64;
#pragma unroll
  for(int cy=0; cy<2; cy++){
#pragma unroll
    for(int cx=0; cx<2; cx++){
      int xi = (int)x0 + cx, yi = (int)y0 + cy;
      float w = (cx ? wx1 : 1.f-wx1) * (cy ? wy1 : 1.f-wy1);
      bool valid = (xi>=0)&&(xi<128)&&(yi>=0)&&(yi<128);
      float wv = valid ? w : 0.f;
      int xc = min(max(xi,0),127), yc = min(max(yi,0),127);
      acc += wv * latb[(size_t)(yc*128 + xc)*64 + lane];
      // fcoord sampling is analytic: ch0 = fy[yc], ch1 = fx[xc]
      qcy += wv * (-1.f + (2.f*(float)yc + 1.f)*(1.f/128.f));
      qcx += wv * (-1.f + (2.f*(float)xc + 1.f)*(1.f/128.f));
    }
  }
  qf[(size_t)pidx*64 + lane] = acc;

  // ---- image sample (256x256, C=1) ----
  float jx = ((x + 1.f)*256.f - 1.f)*0.5f;
  float jy = ((y + 1.f)*256.f - 1.f)*0.5f;
  float jx0 = floorf(jx), jy0 = floorf(jy);
  float ux1 = jx - jx0, uy1 = jy - jy0;
  float acc2 = 0.f;
  const float* imb = image + (size_t)b*256*256;
#pragma unroll
  for(int cy=0; cy<2; cy++){
#pragma unroll
    for(int cx=0; cx<2; cx++){
      int xi = (int)jx0 + cx, yi = (int)jy0 + cy;
      float w = (cx ? ux1 : 1.f-ux1) * (cy ? uy1 : 1.f-uy1);
      bool valid = (xi>=0)&&(xi<256)&&(yi>=0)&&(yi<256);
      int xc = min(max(xi,0),255), yc = min(max(yi,0),255);
      acc2 += (valid ? w : 0.f) * imb[yc*256 + xc];
    }
  }
  size_t obase = (size_t)pidx * 89;
  if(lane == 0) out[obase + 64] = acc2;

  // ---- positional encoding: out[65..88] = [sin(12), cos(12)], d-major then octave ----
  if(lane < 24){
    int r = (lane < 12) ? lane : lane - 12;
    int d = r / 6, o = r % 6;
    float cval = (d == 0) ? qcy : qcx;
    cval = (cval + 1.f) * 0.5f;
    float arg = cval * 3.14159265358979323846f * (float)(1 << o);
    out[obase + 65 + lane] = (lane < 12) ? sinf(arg) : cosf(arg);
  }
}

// Attention: one wave per point, lane = channel. Weights in LDS.
// ctx rows come from uft (transposed qf) so each row is a contiguous 256B read.
__global__ __launch_bounds__(1024) void k_attn(const float* __restrict__ qf,
                                               const float* __restrict__ uft,
                                               const float* __restrict__ wq,
                                               const float* __restrict__ wkv,
                                               const float* __restrict__ wout,
                                               const float* __restrict__ bout,
                                               const float* __restrict__ lsq,
                                               const float* __restrict__ lbq,
                                               const float* __restrict__ lsc,
                                               const float* __restrict__ lbc,
                                               float* __restrict__ out){
  __shared__ float s_wq [64*64];
  __shared__ float s_wkv[64*128];
  __shared__ float s_wout[64*64];
  __shared__ float s_par[5*64];   // lsq | lbq | lsc | lbc | bout
  __shared__ float s_xq[16][64];
  __shared__ float s_cn[16][64];

  const int t = threadIdx.x;
  for(int i=t; i<4096; i+=1024){ s_wq[i] = wq[i]; s_wout[i] = wout[i]; }
  for(int i=t; i<8192; i+=1024){ s_wkv[i] = wkv[i]; }
  if(t < 64){
    s_par[t]       = lsq[t];
    s_par[64 + t]  = lbq[t];
    s_par[128 + t] = lsc[t];
    s_par[192 + t] = lbc[t];
    s_par[256 + t] = bout[t];
  }
  __syncthreads();

  const int wid = t >> 6, lane = t & 63;
  const int p = blockIdx.x * 16 + wid;      // global point id = b*16384 + n
  const int b = p >> 14, n = p & 16383;
  const int h = n >> 7, w = n & 127;

  // LN of the query row
  float qv0 = qf[(size_t)p*64 + lane];
  float s1 = wsum(qv0), s2 = wsum(qv0*qv0);
  float mu = s1 * (1.f/64.f);
  float rs = rsqrtf(s2*(1.f/64.f) - mu*mu + 1e-5f);
  float xq = (qv0 - mu)*rs*s_par[lane] + s_par[64 + lane];
  s_xq[wid][lane] = xq;

  // q = xq @ w_q, scaled by C^-0.5
  float qvl = 0.f;
#pragma unroll 8
  for(int c=0;c<64;c++) qvl += s_xq[wid][c] * s_wq[c*64 + lane];
  qvl *= 0.125f;

  // online softmax over 9 neighbors
  const float* uftb = uft + (size_t)b*16384*64;
  float mrun = -1e30f, se = 0.f, ovl = 0.f;
#pragma unroll
  for(int k=0;k<9;k++){
    int hh = min(max(h + k/3 - 1, 0), 127);
    int ww = min(max(w + k%3 - 1, 0), 127);
    float g = uftb[(size_t)(hh*128 + ww)*64 + lane];
    float g1 = wsum(g), g2 = wsum(g*g);
    float mu2 = g1*(1.f/64.f);
    float rs2 = rsqrtf(g2*(1.f/64.f) - mu2*mu2 + 1e-5f);
    float cn = (g - mu2)*rs2*s_par[128 + lane] + s_par[192 + lane];
    s_cn[wid][lane] = cn;
    float a0 = 0.f, a1 = 0.f;
#pragma unroll 8
    for(int c=0;c<64;c++){
      float cc = s_cn[wid][c];
      a0 += cc * s_wkv[c*128 + lane];
      a1 += cc * s_wkv[c*128 + 64 + lane];
    }
    float simk = wsum(qvl * a0);
    float mnew = fmaxf(mrun, simk);
    float corr = __expf(mrun - mnew);   // first iter: exp(-inf) = 0
    float e    = __expf(simk - mnew);
    se  = se*corr + e;
    ovl = ovl*corr + e*a1;
    mrun = mnew;
  }
  ovl *= (1.f / se);

  // out projection
  s_cn[wid][lane] = ovl;
  float o2 = s_par[256 + lane];
#pragma unroll 8
  for(int c=0;c<64;c++) o2 += s_cn[wid][c] * s_wout[c*64 + lane];
  out[(size_t)p*89 + lane] = o2;
}

extern "C" void kernel_launch(void* const* d_in, const int* in_sizes, int n_in,
                              void* d_out, int out_size, void* d_ws, size_t ws_size,
                              hipStream_t stream){
  const float* image   = (const float*)d_in[0];
  const float* latents = (const float*)d_in[1];
  const float* coords  = (const float*)d_in[2];
  const float* lsq     = (const float*)d_in[3];
  const float* lbq     = (const float*)d_in[4];
  const float* lsc     = (const float*)d_in[5];
  const float* lbc     = (const float*)d_in[6];
  const float* wq      = (const float*)d_in[7];
  const float* wkv     = (const float*)d_in[8];
  const float* wout    = (const float*)d_in[9];
  const float* bout    = (const float*)d_in[10];
  float* out  = (float*)d_out;
  float* buf0 = (float*)d_ws;                  // lat_t, later reused as uft
  float* qfb  = (float*)d_ws + 4194304;        // qf [B][N][C]

  dim3 trg(256, 4);
  // latents [B][C][HW] -> lat_t [B][HW][C]
  k_tr<<<trg, 256, 0, stream>>>(latents, buf0);
  // bilinear sample + extras
  k_sample<<<16384, 256, 0, stream>>>(buf0, coords, image, qfb, out);
  // qf_flat viewed as [64][16384] per batch -> uft [HW'][64] (the "uf" scramble, transposed)
  k_tr<<<trg, 256, 0, stream>>>(qfb, buf0);
  // attention
  k_attn<<<4096, 1024, 0, stream>>>(qfb, buf0, wq, wkv, wout, bout,
                                    lsq, lbq, lsc, lbc, out);
}

// Round 3
// 194.151 us; speedup vs baseline: 3.2031x; 3.2031x over previous
//
#include <hip/hip_runtime.h>
#include <cstdint>

// B=4, C=64, H=W=128, N=16384 points/batch, 65536 total rows, out dim 89.

typedef __attribute__((ext_vector_type(8))) short bf16x8;
typedef __attribute__((ext_vector_type(4))) float f32x4;
typedef __attribute__((ext_vector_type(4))) uint32_t u32x4;

__device__ __forceinline__ float wsum(float v){
#pragma unroll
  for(int o=32;o>0;o>>=1) v += __shfl_xor(v,o,64);
  return v;
}
__device__ __forceinline__ unsigned short f2bf(float x){
  union{float f; uint32_t u;} c; c.f=x;
  uint32_t r = c.u + 0x7fffu + ((c.u>>16)&1u);   // RNE to bf16
  return (unsigned short)(r>>16);
}
__device__ __forceinline__ float bf2f(unsigned short h){
  union{uint32_t u; float f;} c; c.u = ((uint32_t)h)<<16; return c.f;
}

// -------- 1. latents [C][HW] -> lat_t [HW][C] (fp32 transpose) --------
__global__ __launch_bounds__(256) void k_tr(const float* __restrict__ in,
                                            float* __restrict__ out){
  __shared__ float t[64][65];
  const int b  = blockIdx.y;
  const int p0 = blockIdx.x * 64;
  const float* src = in  + (size_t)b * (64 * 16384);
  float*       dst = out + (size_t)b * (64 * 16384);
  const int tx = threadIdx.x & 63, ty = threadIdx.x >> 6;
#pragma unroll
  for(int j=0;j<16;j++){ int r = ty + j*4; t[r][tx] = src[(size_t)r*16384 + p0 + tx]; }
  __syncthreads();
#pragma unroll
  for(int j=0;j<16;j++){ int pr = ty + j*4; dst[(size_t)(p0+pr)*64 + tx] = t[tx][pr]; }
}

// -------- 2. bilinear sample + extras + LN(q) -> XQ (bf16, swizzled) --------
// qf written bf16 [p][64] for the transpose pass; XQ is swizzled bf16-pair rows.
__global__ __launch_bounds__(256) void k_sample(const float* __restrict__ lat_t,
                                                const float* __restrict__ coords,
                                                const float* __restrict__ image,
                                                const float* __restrict__ lsq,
                                                const float* __restrict__ lbq,
                                                uint16_t* __restrict__ qf,
                                                uint32_t* __restrict__ xq,
                                                float* __restrict__ out){
  const int lane = threadIdx.x & 63;
  const int pidx = blockIdx.x * 4 + (threadIdx.x >> 6);
  const int b = pidx >> 14;
  const float y = coords[(size_t)pidx*2 + 0];
  const float x = coords[(size_t)pidx*2 + 1];

  float ix = ((x + 1.f)*128.f - 1.f)*0.5f;
  float iy = ((y + 1.f)*128.f - 1.f)*0.5f;
  float x0 = floorf(ix), y0 = floorf(iy);
  float wx1 = ix - x0, wy1 = iy - y0;
  float acc = 0.f, qcy = 0.f, qcx = 0.f;
  const float* latb = lat_t + (size_t)b*16384*64;
#pragma unroll
  for(int cy=0; cy<2; cy++){
#pragma unroll
    for(int cx=0; cx<2; cx++){
      int xi = (int)x0 + cx, yi = (int)y0 + cy;
      float w = (cx ? wx1 : 1.f-wx1) * (cy ? wy1 : 1.f-wy1);
      bool valid = (xi>=0)&&(xi<128)&&(yi>=0)&&(yi<128);
      float wv = valid ? w : 0.f;
      int xc = min(max(xi,0),127), yc = min(max(yi,0),127);
      acc += wv * latb[(size_t)(yc*128 + xc)*64 + lane];
      qcy += wv * (-1.f + (2.f*(float)yc + 1.f)*(1.f/128.f));
      qcx += wv * (-1.f + (2.f*(float)xc + 1.f)*(1.f/128.f));
    }
  }
  qf[(size_t)pidx*64 + lane] = f2bf(acc);

  // LN(q) -> XQ bf16 swizzled (granule 16B XOR key row&7)
  float s1 = wsum(acc), s2 = wsum(acc*acc);
  float mu = s1*(1.f/64.f);
  float rs = rsqrtf(s2*(1.f/64.f) - mu*mu + 1e-5f);
  float xv = (acc - mu)*rs*lsq[lane] + lbq[lane];
  float va = __shfl(xv, (lane&31)*2), vb = __shfl(xv, (lane&31)*2+1);
  if(lane < 32)
    xq[(size_t)pidx*32 + (lane ^ ((pidx&7)<<2))] = ((uint32_t)f2bf(vb)<<16) | f2bf(va);

  // image sample (256x256, C=1)
  float jx = ((x + 1.f)*256.f - 1.f)*0.5f;
  float jy = ((y + 1.f)*256.f - 1.f)*0.5f;
  float jx0 = floorf(jx), jy0 = floorf(jy);
  float ux1 = jx - jx0, uy1 = jy - jy0;
  float acc2 = 0.f;
  const float* imb = image + (size_t)b*256*256;
#pragma unroll
  for(int cy=0; cy<2; cy++){
#pragma unroll
    for(int cx=0; cx<2; cx++){
      int xi = (int)jx0 + cx, yi = (int)jy0 + cy;
      float w = (cx ? ux1 : 1.f-ux1) * (cy ? uy1 : 1.f-uy1);
      bool valid = (xi>=0)&&(xi<256)&&(yi>=0)&&(yi<256);
      int xc = min(max(xi,0),255), yc = min(max(yi,0),255);
      acc2 += (valid ? w : 0.f) * imb[yc*256 + xc];
    }
  }
  size_t obase = (size_t)pidx * 89;
  if(lane == 0) out[obase + 64] = acc2;

  if(lane < 24){
    int r = (lane < 12) ? lane : lane - 12;
    int d = r / 6, o = r % 6;
    float cval = (d == 0) ? qcy : qcx;
    cval = (cval + 1.f) * 0.5f;
    float arg = cval * 3.14159265358979323846f * (float)(1 << o);
    out[obase + 65 + lane] = (lane < 12) ? sinf(arg) : cosf(arg);
  }
}

// -------- 3. transpose(qf as [64][16384]) + LN -> CN (bf16, swizzled) --------
__global__ __launch_bounds__(256) void k_tr_ln(const uint16_t* __restrict__ qf,
                                               const float* __restrict__ lsc,
                                               const float* __restrict__ lbc,
                                               uint32_t* __restrict__ cn){
  __shared__ float t[64][65];
  const int b  = blockIdx.y;
  const int p0 = blockIdx.x * 64;
  const uint16_t* src = qf + (size_t)b * 1048576;
  const int tx = threadIdx.x & 63, ty = threadIdx.x >> 6;
  const float sc = lsc[tx], bc = lbc[tx];
#pragma unroll
  for(int j=0;j<16;j++){ int r = ty + j*4; t[r][tx] = bf2f(src[(size_t)r*16384 + p0 + tx]); }
  __syncthreads();
#pragma unroll
  for(int j=0;j<16;j++){
    int pr = ty + j*4;
    float v = t[tx][pr];
    float s1 = wsum(v), s2 = wsum(v*v);
    float mu = s1*(1.f/64.f);
    float rs = rsqrtf(s2*(1.f/64.f) - mu*mu + 1e-5f);
    float cv = (v - mu)*rs*sc + bc;
    float va = __shfl(cv, (tx&31)*2), vb = __shfl(cv, (tx&31)*2+1);
    int rown = p0 + pr;                       // low bits identical to global row
    size_t row = (size_t)b*16384 + rown;
    if(tx < 32)
      cn[row*32 + (tx ^ ((rown&7)<<2))] = ((uint32_t)f2bf(vb)<<16) | f2bf(va);
  }
}

// -------- 4/5/7. MFMA GEMM: C[65536 x N] = A[65536 x 64] @ W[64 x N] --------
// A is bf16-pair u32 rows (32 u32 = 128B), XOR-swizzled by producer.
// MODE 0: Q   = A@Wq * 0.125 -> bf16 [row][64]
// MODE 1: K|V = A@Wkv        -> bf16 [row][64] each
// MODE 2: out = A@Wout + b   -> fp32 out[row*89 + col]
template<int MODE>
__global__ __launch_bounds__(256) void k_gemm(const uint32_t* A, const float* W,
                                              const float* bias,
                                              uint16_t* oK, uint16_t* oV, float* oF){
  constexpr int N  = (MODE==1) ? 128 : 64;
  constexpr int NT = (MODE==1) ? 2 : 1;       // n-tiles per wave (4 waves)
  __shared__ uint32_t la[128*32];             // 128 rows x 128B (swizzled content)
  const int t  = threadIdx.x;
  const int wv = t >> 6, ln = t & 63;
  const uint32_t* src = A + (size_t)blockIdx.x * 4096;
#pragma unroll
  for(int i=0;i<4;i++){
    *(u32x4*)&la[(i*256+t)*4] = *(const u32x4*)&src[(i*256+t)*4];
  }
  // B fragments (fp32 weights -> bf16), resident in VGPRs
  bf16x8 bfr[NT][2];
#pragma unroll
  for(int nt=0;nt<NT;nt++){
    const int ntg = wv*NT + nt;
#pragma unroll
    for(int ks=0;ks<2;ks++){
#pragma unroll
      for(int e=0;e<8;e++){
        int k = ks*32 + (ln>>4)*8 + e;
        bfr[nt][ks][e] = (short)f2bf(W[(size_t)k*N + ntg*16 + (ln&15)]);
      }
    }
  }
  __syncthreads();

  f32x4 acc[8][NT];
#pragma unroll
  for(int m=0;m<8;m++)
#pragma unroll
    for(int nt=0;nt<NT;nt++) acc[m][nt] = (f32x4){0.f,0.f,0.f,0.f};

#pragma unroll
  for(int m=0;m<8;m++){
    const int R = m*16 + (ln&15);
#pragma unroll
    for(int ks=0;ks<2;ks++){
      const int gs = (ks*4 + (ln>>4)) ^ (R&7);  // undo producer swizzle
      bf16x8 af = *(const bf16x8*)&la[R*32 + gs*4];
#pragma unroll
      for(int nt=0;nt<NT;nt++)
        acc[m][nt] = __builtin_amdgcn_mfma_f32_16x16x32_bf16(af, bfr[nt][ks], acc[m][nt], 0,0,0);
    }
  }

  const size_t r0 = (size_t)blockIdx.x * 128;
#pragma unroll
  for(int m=0;m<8;m++){
#pragma unroll
    for(int nt=0;nt<NT;nt++){
      const int ntg = wv*NT + nt;
      const int col = ntg*16 + (ln&15);
#pragma unroll
      for(int r=0;r<4;r++){
        const size_t row = r0 + m*16 + (ln>>4)*4 + r;
        float v = acc[m][nt][r];
        if constexpr (MODE==0){
          oK[row*64 + col] = f2bf(v * 0.125f);
        } else if constexpr (MODE==1){
          if(col < 64) oK[row*64 + col]      = f2bf(v);
          else         oV[row*64 + (col-64)] = f2bf(v);
        } else {
          oF[row*89 + col] = v + bias[col];
        }
      }
    }
  }
}

// -------- 6. attention: wave=point, lane=channel --------
__global__ __launch_bounds__(256) void k_attn2(const uint16_t* __restrict__ Qb,
                                               const uint16_t* __restrict__ Kb,
                                               const uint16_t* __restrict__ Vb,
                                               uint32_t* __restrict__ O){
  const int ln = threadIdx.x & 63;
  const int p  = blockIdx.x * 4 + (threadIdx.x >> 6);
  const int b = p >> 14, n = p & 16383, h = n >> 7, w = n & 127;
  const float q = bf2f(Qb[(size_t)p*64 + ln]);
  const size_t base = (size_t)b * 16384;
  float mrun = -1e30f, se = 0.f, ovl = 0.f;
#pragma unroll
  for(int k=0;k<9;k++){
    int hh = min(max(h + k/3 - 1, 0), 127);
    int ww = min(max(w + k%3 - 1, 0), 127);
    size_t pos = base + hh*128 + ww;
    float kv = bf2f(Kb[pos*64 + ln]);
    float sim = wsum(q * kv);
    float vv = bf2f(Vb[pos*64 + ln]);
    float mnew = fmaxf(mrun, sim);
    float corr = __expf(mrun - mnew);
    float e    = __expf(sim - mnew);
    se  = se*corr + e;
    ovl = ovl*corr + e*vv;
    mrun = mnew;
  }
  ovl *= 1.f/se;
  float va = __shfl(ovl, (ln&31)*2), vb = __shfl(ovl, (ln&31)*2+1);
  if(ln < 32)
    O[(size_t)p*32 + (ln ^ ((p&7)<<2))] = ((uint32_t)f2bf(vb)<<16) | f2bf(va);
}

extern "C" void kernel_launch(void* const* d_in, const int* in_sizes, int n_in,
                              void* d_out, int out_size, void* d_ws, size_t ws_size,
                              hipStream_t stream){
  const float* image   = (const float*)d_in[0];
  const float* latents = (const float*)d_in[1];
  const float* coords  = (const float*)d_in[2];
  const float* lsq     = (const float*)d_in[3];
  const float* lbq     = (const float*)d_in[4];
  const float* lsc     = (const float*)d_in[5];
  const float* lbc     = (const float*)d_in[6];
  const float* wq      = (const float*)d_in[7];
  const float* wkv     = (const float*)d_in[8];
  const float* wout    = (const float*)d_in[9];
  const float* bout    = (const float*)d_in[10];
  float* out = (float*)d_out;

  // Workspace (33,554,432 B total), regions reused as producers die:
  //   [0, 16.8M): lat_t fp32 -> CN (8.4M, after k_sample) -> K in-place; V at +8.4M
  //   [16.8M, 25.2M): qf bf16 -> O (after k_tr_ln)
  //   [25.2M, 33.6M): XQ -> Q in-place
  char* ws = (char*)d_ws;
  float*    latT = (float*)ws;
  uint32_t* CN   = (uint32_t*)ws;
  uint16_t* Kb   = (uint16_t*)ws;
  uint16_t* Vb   = (uint16_t*)(ws + 8388608);
  uint16_t* qfB  = (uint16_t*)(ws + 16777216);
  uint32_t* O    = (uint32_t*)(ws + 16777216);
  uint32_t* XQ   = (uint32_t*)(ws + 25165824);
  uint16_t* Qb   = (uint16_t*)(ws + 25165824);

  dim3 trg(256, 4);
  k_tr    <<<trg,   256, 0, stream>>>(latents, latT);
  k_sample<<<16384, 256, 0, stream>>>(latT, coords, image, lsq, lbq, qfB, XQ, out);
  k_tr_ln <<<trg,   256, 0, stream>>>(qfB, lsc, lbc, CN);
  k_gemm<0><<<512,  256, 0, stream>>>(XQ, wq,  nullptr, Qb, nullptr, nullptr);
  k_gemm<1><<<512,  256, 0, stream>>>(CN, wkv, nullptr, Kb, Vb,      nullptr);
  k_attn2 <<<16384, 256, 0, stream>>>(Qb, Kb, Vb, O);
  k_gemm<2><<<512,  256, 0, stream>>>(O, wout, bout, nullptr, nullptr, out);
}

// Round 5
// 168.945 us; speedup vs baseline: 3.6810x; 1.1492x over previous
//
#include <hip/hip_runtime.h>
#include <cstdint>

// B=4, C=64, H=W=128, N=16384 points/batch, 65536 total rows, out dim 89.

typedef __attribute__((ext_vector_type(8))) short bf16x8;
typedef __attribute__((ext_vector_type(4))) float f32x4;
typedef __attribute__((ext_vector_type(4))) uint32_t u32x4;
typedef __attribute__((ext_vector_type(2))) uint32_t u32x2;

__device__ __forceinline__ float wsum(float v){
#pragma unroll
  for(int o=32;o>0;o>>=1) v += __shfl_xor(v,o,64);
  return v;
}
__device__ __forceinline__ unsigned short f2bf(float x){
  union{float f; uint32_t u;} c; c.f=x;
  uint32_t r = c.u + 0x7fffu + ((c.u>>16)&1u);   // RNE to bf16
  return (unsigned short)(r>>16);
}
__device__ __forceinline__ float bf2f(unsigned short h){
  union{uint32_t u; float f;} c; c.u = ((uint32_t)h)<<16; return c.f;
}
__device__ __forceinline__ float blo(uint32_t u){
  union{uint32_t x; float f;} c; c.x = u<<16; return c.f;
}
__device__ __forceinline__ float bhi(uint32_t u){
  union{uint32_t x; float f;} c; c.x = u & 0xffff0000u; return c.f;
}

// -------- 1. latents [C][HW] -> lat_t [HW][C] (fp32 -> bf16 transpose) --------
__global__ __launch_bounds__(256) void k_tr_bf(const float* __restrict__ in,
                                               uint16_t* __restrict__ out){
  __shared__ float t[64][65];
  const int b  = blockIdx.y;
  const int p0 = blockIdx.x * 64;
  const float* src = in  + (size_t)b * (64 * 16384);
  uint16_t*    dst = out + (size_t)b * (64 * 16384);
  const int tx = threadIdx.x & 63, ty = threadIdx.x >> 6;
#pragma unroll
  for(int j=0;j<16;j++){ int r = ty + j*4; t[r][tx] = src[(size_t)r*16384 + p0 + tx]; }
  __syncthreads();
#pragma unroll
  for(int j=0;j<16;j++){ int pr = ty + j*4; dst[(size_t)(p0+pr)*64 + tx] = f2bf(t[tx][pr]); }
}

// -------- 2. bilinear sample (bf16 latT) + extras + LN(q) -> XQ --------
__global__ __launch_bounds__(256) void k_sample(const uint16_t* __restrict__ lat_t,
                                                const float* __restrict__ coords,
                                                const float* __restrict__ image,
                                                const float* __restrict__ lsq,
                                                const float* __restrict__ lbq,
                                                uint16_t* __restrict__ qf,
                                                uint32_t* __restrict__ xq,
                                                float* __restrict__ out){
  const int lane = threadIdx.x & 63;
  const int pidx = blockIdx.x * 4 + (threadIdx.x >> 6);
  const int b = pidx >> 14;
  const float y = coords[(size_t)pidx*2 + 0];
  const float x = coords[(size_t)pidx*2 + 1];

  float ix = ((x + 1.f)*128.f - 1.f)*0.5f;
  float iy = ((y + 1.f)*128.f - 1.f)*0.5f;
  float x0 = floorf(ix), y0 = floorf(iy);
  float wx1 = ix - x0, wy1 = iy - y0;
  float acc = 0.f, qcy = 0.f, qcx = 0.f;
  const uint16_t* latb = lat_t + (size_t)b*16384*64;
#pragma unroll
  for(int cy=0; cy<2; cy++){
#pragma unroll
    for(int cx=0; cx<2; cx++){
      int xi = (int)x0 + cx, yi = (int)y0 + cy;
      float w = (cx ? wx1 : 1.f-wx1) * (cy ? wy1 : 1.f-wy1);
      bool valid = (xi>=0)&&(xi<128)&&(yi>=0)&&(yi<128);
      float wv = valid ? w : 0.f;
      int xc = min(max(xi,0),127), yc = min(max(yi,0),127);
      acc += wv * bf2f(latb[(size_t)(yc*128 + xc)*64 + lane]);
      qcy += wv * (-1.f + (2.f*(float)yc + 1.f)*(1.f/128.f));
      qcx += wv * (-1.f + (2.f*(float)xc + 1.f)*(1.f/128.f));
    }
  }
  qf[(size_t)pidx*64 + lane] = f2bf(acc);

  // LN(q) -> XQ bf16-pair u32, XOR-swizzled (granule 16B, key row&7)
  float s1 = wsum(acc), s2 = wsum(acc*acc);
  float mu = s1*(1.f/64.f);
  float rs = rsqrtf(s2*(1.f/64.f) - mu*mu + 1e-5f);
  float xv = (acc - mu)*rs*lsq[lane] + lbq[lane];
  float va = __shfl(xv, (lane&31)*2), vb = __shfl(xv, (lane&31)*2+1);
  if(lane < 32)
    xq[(size_t)pidx*32 + (lane ^ ((pidx&7)<<2))] = ((uint32_t)f2bf(vb)<<16) | f2bf(va);

  // image sample (256x256, C=1)
  float jx = ((x + 1.f)*256.f - 1.f)*0.5f;
  float jy = ((y + 1.f)*256.f - 1.f)*0.5f;
  float jx0 = floorf(jx), jy0 = floorf(jy);
  float ux1 = jx - jx0, uy1 = jy - jy0;
  float acc2 = 0.f;
  const float* imb = image + (size_t)b*256*256;
#pragma unroll
  for(int cy=0; cy<2; cy++){
#pragma unroll
    for(int cx=0; cx<2; cx++){
      int xi = (int)jx0 + cx, yi = (int)jy0 + cy;
      float w = (cx ? ux1 : 1.f-ux1) * (cy ? uy1 : 1.f-uy1);
      bool valid = (xi>=0)&&(xi<256)&&(yi>=0)&&(yi<256);
      int xc = min(max(xi,0),255), yc = min(max(yi,0),255);
      acc2 += (valid ? w : 0.f) * imb[yc*256 + xc];
    }
  }
  size_t obase = (size_t)pidx * 89;
  if(lane == 0) out[obase + 64] = acc2;

  if(lane < 24){
    int r = (lane < 12) ? lane : lane - 12;
    int d = r / 6, o = r % 6;
    float cval = (d == 0) ? qcy : qcx;
    cval = (cval + 1.f) * 0.5f;
    float arg = cval * 3.14159265358979323846f * (float)(1 << o);
    out[obase + 65 + lane] = (lane < 12) ? sinf(arg) : cosf(arg);
  }
}

// -------- 3. transpose(qf as [64][16384]) + LN -> CN (bf16, swizzled) --------
__global__ __launch_bounds__(256) void k_tr_ln(const uint16_t* __restrict__ qf,
                                               const float* __restrict__ lsc,
                                               const float* __restrict__ lbc,
                                               uint32_t* __restrict__ cn){
  __shared__ float t[64][65];
  const int b  = blockIdx.y;
  const int p0 = blockIdx.x * 64;
  const uint16_t* src = qf + (size_t)b * 1048576;
  const int tx = threadIdx.x & 63, ty = threadIdx.x >> 6;
  const float sc = lsc[tx], bc = lbc[tx];
#pragma unroll
  for(int j=0;j<16;j++){ int r = ty + j*4; t[r][tx] = bf2f(src[(size_t)r*16384 + p0 + tx]); }
  __syncthreads();
#pragma unroll
  for(int j=0;j<16;j++){
    int pr = ty + j*4;
    float v = t[tx][pr];
    float s1 = wsum(v), s2 = wsum(v*v);
    float mu = s1*(1.f/64.f);
    float rs = rsqrtf(s2*(1.f/64.f) - mu*mu + 1e-5f);
    float cv = (v - mu)*rs*sc + bc;
    float va = __shfl(cv, (tx&31)*2), vb = __shfl(cv, (tx&31)*2+1);
    int rown = p0 + pr;
    size_t row = (size_t)b*16384 + rown;
    if(tx < 32)
      cn[row*32 + (tx ^ ((rown&7)<<2))] = ((uint32_t)f2bf(vb)<<16) | f2bf(va);
  }
}

// -------- 4/5/7. MFMA GEMM: C[65536 x N] = A[65536 x 64] @ W[64 x N] --------
template<int MODE>
__global__ __launch_bounds__(256) void k_gemm(const uint32_t* A, const float* W,
                                              const float* bias,
                                              uint16_t* oK, uint16_t* oV, float* oF){
  constexpr int N  = (MODE==1) ? 128 : 64;
  constexpr int NT = (MODE==1) ? 2 : 1;
  __shared__ uint32_t la[128*32];
  const int t  = threadIdx.x;
  const int wv = t >> 6, ln = t & 63;
  const uint32_t* src = A + (size_t)blockIdx.x * 4096;
#pragma unroll
  for(int i=0;i<4;i++){
    *(u32x4*)&la[(i*256+t)*4] = *(const u32x4*)&src[(i*256+t)*4];
  }
  bf16x8 bfr[NT][2];
#pragma unroll
  for(int nt=0;nt<NT;nt++){
    const int ntg = wv*NT + nt;
#pragma unroll
    for(int ks=0;ks<2;ks++){
#pragma unroll
      for(int e=0;e<8;e++){
        int k = ks*32 + (ln>>4)*8 + e;
        bfr[nt][ks][e] = (short)f2bf(W[(size_t)k*N + ntg*16 + (ln&15)]);
      }
    }
  }
  __syncthreads();

  f32x4 acc[8][NT];
#pragma unroll
  for(int m=0;m<8;m++)
#pragma unroll
    for(int nt=0;nt<NT;nt++) acc[m][nt] = (f32x4){0.f,0.f,0.f,0.f};

#pragma unroll
  for(int m=0;m<8;m++){
    const int R = m*16 + (ln&15);
#pragma unroll
    for(int ks=0;ks<2;ks++){
      const int gs = (ks*4 + (ln>>4)) ^ (R&7);
      bf16x8 af = *(const bf16x8*)&la[R*32 + gs*4];
#pragma unroll
      for(int nt=0;nt<NT;nt++)
        acc[m][nt] = __builtin_amdgcn_mfma_f32_16x16x32_bf16(af, bfr[nt][ks], acc[m][nt], 0,0,0);
    }
  }

  const size_t r0 = (size_t)blockIdx.x * 128;
#pragma unroll
  for(int m=0;m<8;m++){
#pragma unroll
    for(int nt=0;nt<NT;nt++){
      const int ntg = wv*NT + nt;
      const int col = ntg*16 + (ln&15);
#pragma unroll
      for(int r=0;r<4;r++){
        const size_t row = r0 + m*16 + (ln>>4)*4 + r;
        float v = acc[m][nt][r];
        if constexpr (MODE==0){
          oK[row*64 + col] = f2bf(v * 0.125f);
        } else if constexpr (MODE==1){
          if(col < 64) oK[row*64 + col]      = f2bf(v);
          else         oV[row*64 + (col-64)] = f2bf(v);
        } else {
          oF[row*89 + col] = v + bias[col];
        }
      }
    }
  }
}

// -------- 6. attention: 4 points/wave, 16 lanes/point, 4 channels/lane --------
__global__ __launch_bounds__(256) void k_attn3(const uint16_t* __restrict__ Qb,
                                               const uint16_t* __restrict__ Kb,
                                               const uint16_t* __restrict__ Vb,
                                               uint32_t* __restrict__ O){
  const int t  = threadIdx.x;
  const int ln = t & 63;
  const int cl = ln & 15;                         // channels 4cl..4cl+3
  const int p  = blockIdx.x*16 + (t>>6)*4 + (ln>>4);
  const int b = p >> 14, n = p & 16383, h = n >> 7, w = n & 127;

  u32x2 qp = *(const u32x2*)((const char*)Qb + (size_t)p*128 + cl*8);
  const float q0 = blo(qp.x), q1 = bhi(qp.x), q2 = blo(qp.y), q3 = bhi(qp.y);

  const size_t base = (size_t)b * 16384;
  float sim[9];
  uint32_t v01[9], v23[9];
#pragma unroll
  for(int k=0;k<9;k++){
    int hh = min(max(h + k/3 - 1, 0), 127);
    int ww = min(max(w + k%3 - 1, 0), 127);
    size_t pos = base + hh*128 + ww;
    u32x2 kp = *(const u32x2*)((const char*)Kb + pos*128 + cl*8);
    u32x2 vp = *(const u32x2*)((const char*)Vb + pos*128 + cl*8);
    v01[k] = vp.x; v23[k] = vp.y;
    float s = q0*blo(kp.x) + q1*bhi(kp.x) + q2*blo(kp.y) + q3*bhi(kp.y);
#pragma unroll
    for(int o=8;o>0;o>>=1) s += __shfl_xor(s, o, 64);   // 16-lane group reduce
    sim[k] = s;
  }
  float m = sim[0];
#pragma unroll
  for(int k=1;k<9;k++) m = fmaxf(m, sim[k]);
  float se = 0.f, o0 = 0.f, o1 = 0.f, o2 = 0.f, o3 = 0.f;
#pragma unroll
  for(int k=0;k<9;k++){
    float e = __expf(sim[k] - m);
    se += e;
    o0 += e*blo(v01[k]); o1 += e*bhi(v01[k]);
    o2 += e*blo(v23[k]); o3 += e*bhi(v23[k]);
  }
  float inv = 1.f/se;
  o0 *= inv; o1 *= inv; o2 *= inv; o3 *= inv;
  const uint32_t w01 = ((uint32_t)f2bf(o1)<<16) | f2bf(o0);
  const uint32_t w23 = ((uint32_t)f2bf(o3)<<16) | f2bf(o2);
  const int key = (p&7)<<2;                        // same swizzle as other producers
  O[(size_t)p*32 + ((cl*2  ) ^ key)] = w01;
  O[(size_t)p*32 + ((cl*2+1) ^ key)] = w23;
}

extern "C" void kernel_launch(void* const* d_in, const int* in_sizes, int n_in,
                              void* d_out, int out_size, void* d_ws, size_t ws_size,
                              hipStream_t stream){
  const float* image   = (const float*)d_in[0];
  const float* latents = (const float*)d_in[1];
  const float* coords  = (const float*)d_in[2];
  const float* lsq     = (const float*)d_in[3];
  const float* lbq     = (const float*)d_in[4];
  const float* lsc     = (const float*)d_in[5];
  const float* lbc     = (const float*)d_in[6];
  const float* wq      = (const float*)d_in[7];
  const float* wkv     = (const float*)d_in[8];
  const float* wout    = (const float*)d_in[9];
  const float* bout    = (const float*)d_in[10];
  float* out = (float*)d_out;

  // Workspace regions (33.5 MB), reused as producers die:
  //   [0, 8.4M):      latT bf16 -> CN (after k_sample) -> Kb in-place
  //   [8.4M, 16.8M):  Vb
  //   [16.8M, 25.2M): qf bf16 -> O (after k_tr_ln)
  //   [25.2M, 33.6M): XQ -> Qb in-place
  char* ws = (char*)d_ws;
  uint16_t* latT = (uint16_t*)ws;
  uint32_t* CN   = (uint32_t*)ws;
  uint16_t* Kb   = (uint16_t*)ws;
  uint16_t* Vb   = (uint16_t*)(ws + 8388608);
  uint16_t* qfB  = (uint16_t*)(ws + 16777216);
  uint32_t* O    = (uint32_t*)(ws + 16777216);
  uint32_t* XQ   = (uint32_t*)(ws + 25165824);
  uint16_t* Qb   = (uint16_t*)(ws + 25165824);

  dim3 trg(256, 4);
  k_tr_bf <<<trg,   256, 0, stream>>>(latents, latT);
  k_sample<<<16384, 256, 0, stream>>>(latT, coords, image, lsq, lbq, qfB, XQ, out);
  k_tr_ln <<<trg,   256, 0, stream>>>(qfB, lsc, lbc, CN);
  k_gemm<0><<<512,  256, 0, stream>>>(XQ, wq,  nullptr, Qb, nullptr, nullptr);
  k_gemm<1><<<512,  256, 0, stream>>>(CN, wkv, nullptr, Kb, Vb,      nullptr);
  k_attn3 <<<4096,  256, 0, stream>>>(Qb, Kb, Vb, O);
  k_gemm<2><<<512,  256, 0, stream>>>(O, wout, bout, nullptr, nullptr, out);
}

// Round 6
// 158.702 us; speedup vs baseline: 3.9186x; 1.0645x over previous
//
#include <hip/hip_runtime.h>
#include <cstdint>

// B=4, C=64, H=W=128, N=16384 points/batch, 65536 total rows, out dim 89.

typedef __attribute__((ext_vector_type(8))) short bf16x8;
typedef __attribute__((ext_vector_type(4))) float f32x4;
typedef __attribute__((ext_vector_type(2))) float f32x2;
typedef __attribute__((ext_vector_type(4))) uint32_t u32x4;
typedef __attribute__((ext_vector_type(2))) uint32_t u32x2;

__device__ __forceinline__ float wsum(float v){
#pragma unroll
  for(int o=32;o>0;o>>=1) v += __shfl_xor(v,o,64);
  return v;
}
__device__ __forceinline__ unsigned short f2bf(float x){
  union{float f; uint32_t u;} c; c.f=x;
  uint32_t r = c.u + 0x7fffu + ((c.u>>16)&1u);   // RNE to bf16
  return (unsigned short)(r>>16);
}
__device__ __forceinline__ float bf2f(unsigned short h){
  union{uint32_t u; float f;} c; c.u = ((uint32_t)h)<<16; return c.f;
}
__device__ __forceinline__ float blo(uint32_t u){
  union{uint32_t x; float f;} c; c.x = u<<16; return c.f;
}
__device__ __forceinline__ float bhi(uint32_t u){
  union{uint32_t x; float f;} c; c.x = u & 0xffff0000u; return c.f;
}

// -------- K1: latents [C][HW] -> lat_t [HW][C] (fp32 -> bf16 transpose) --------
__global__ __launch_bounds__(256) void k_tr_bf(const float* __restrict__ in,
                                               uint16_t* __restrict__ out){
  __shared__ float t[64][65];
  const int b  = blockIdx.y;
  const int p0 = blockIdx.x * 64;
  const float* src = in  + (size_t)b * (64 * 16384);
  uint16_t*    dst = out + (size_t)b * (64 * 16384);
  const int tx = threadIdx.x & 63, ty = threadIdx.x >> 6;
#pragma unroll
  for(int j=0;j<16;j++){ int r = ty + j*4; t[r][tx] = src[(size_t)r*16384 + p0 + tx]; }
  __syncthreads();
#pragma unroll
  for(int j=0;j<16;j++){ int pr = ty + j*4; dst[(size_t)(p0+pr)*64 + tx] = f2bf(t[tx][pr]); }
}

// -------- K2: bilinear sample + extras + LN(q) -> XQ --------
__global__ __launch_bounds__(256) void k_sample(const uint16_t* __restrict__ lat_t,
                                                const float* __restrict__ coords,
                                                const float* __restrict__ image,
                                                const float* __restrict__ lsq,
                                                const float* __restrict__ lbq,
                                                uint16_t* __restrict__ qf,
                                                uint32_t* __restrict__ xq,
                                                float* __restrict__ out){
  const int lane = threadIdx.x & 63;
  const int pidx = blockIdx.x * 4 + (threadIdx.x >> 6);
  const int b = pidx >> 14;
  const float y = coords[(size_t)pidx*2 + 0];
  const float x = coords[(size_t)pidx*2 + 1];

  float ix = ((x + 1.f)*128.f - 1.f)*0.5f;
  float iy = ((y + 1.f)*128.f - 1.f)*0.5f;
  float x0 = floorf(ix), y0 = floorf(iy);
  float wx1 = ix - x0, wy1 = iy - y0;
  float acc = 0.f, qcy = 0.f, qcx = 0.f;
  const uint16_t* latb = lat_t + (size_t)b*16384*64;
#pragma unroll
  for(int cy=0; cy<2; cy++){
#pragma unroll
    for(int cx=0; cx<2; cx++){
      int xi = (int)x0 + cx, yi = (int)y0 + cy;
      float w = (cx ? wx1 : 1.f-wx1) * (cy ? wy1 : 1.f-wy1);
      bool valid = (xi>=0)&&(xi<128)&&(yi>=0)&&(yi<128);
      float wv = valid ? w : 0.f;
      int xc = min(max(xi,0),127), yc = min(max(yi,0),127);
      acc += wv * bf2f(latb[(size_t)(yc*128 + xc)*64 + lane]);
      qcy += wv * (-1.f + (2.f*(float)yc + 1.f)*(1.f/128.f));
      qcx += wv * (-1.f + (2.f*(float)xc + 1.f)*(1.f/128.f));
    }
  }
  qf[(size_t)pidx*64 + lane] = f2bf(acc);

  float s1 = wsum(acc), s2 = wsum(acc*acc);
  float mu = s1*(1.f/64.f);
  float rs = rsqrtf(s2*(1.f/64.f) - mu*mu + 1e-5f);
  float xv = (acc - mu)*rs*lsq[lane] + lbq[lane];
  float va = __shfl(xv, (lane&31)*2), vb = __shfl(xv, (lane&31)*2+1);
  if(lane < 32)
    xq[(size_t)pidx*32 + (lane ^ ((pidx&7)<<2))] = ((uint32_t)f2bf(vb)<<16) | f2bf(va);

  float jx = ((x + 1.f)*256.f - 1.f)*0.5f;
  float jy = ((y + 1.f)*256.f - 1.f)*0.5f;
  float jx0 = floorf(jx), jy0 = floorf(jy);
  float ux1 = jx - jx0, uy1 = jy - jy0;
  float acc2 = 0.f;
  const float* imb = image + (size_t)b*256*256;
#pragma unroll
  for(int cy=0; cy<2; cy++){
#pragma unroll
    for(int cx=0; cx<2; cx++){
      int xi = (int)jx0 + cx, yi = (int)jy0 + cy;
      float w = (cx ? ux1 : 1.f-ux1) * (cy ? uy1 : 1.f-uy1);
      bool valid = (xi>=0)&&(xi<256)&&(yi>=0)&&(yi<256);
      int xc = min(max(xi,0),255), yc = min(max(yi,0),255);
      acc2 += (valid ? w : 0.f) * imb[yc*256 + xc];
    }
  }
  size_t obase = (size_t)pidx * 89;
  if(lane == 0) out[obase + 64] = acc2;

  if(lane < 24){
    int r = (lane < 12) ? lane : lane - 12;
    int d = r / 6, o = r % 6;
    float cval = (d == 0) ? qcy : qcx;
    cval = (cval + 1.f) * 0.5f;
    float arg = cval * 3.14159265358979323846f * (float)(1 << o);
    out[obase + 65 + lane] = (lane < 12) ? sinf(arg) : cosf(arg);
  }
}

// -------- K3: fused {view-transpose + LN_c + KV-GEMM} + {Q-GEMM} --------
// One block = 128 consecutive positions of one batch. 256 threads (4 waves).
__global__ __launch_bounds__(256) void k_proj(const uint16_t* __restrict__ qf,
                                              const uint32_t* __restrict__ XQ,
                                              const float* __restrict__ lsc,
                                              const float* __restrict__ lbc,
                                              const float* __restrict__ wq,
                                              const float* __restrict__ wkv,
                                              uint16_t* __restrict__ Qb,
                                              uint16_t* __restrict__ Kb,
                                              uint16_t* __restrict__ Vb){
  __shared__ float tile[64][130];          // 33.3 KB (pitch 130: 8B-aligned rows, 2-way free)
  __shared__ uint32_t Acn[128*32];         // 16 KB swizzled A (context LN)
  uint32_t* Axq = (uint32_t*)&tile[0][0];  // aliases tile after phase B

  const int t   = threadIdx.x;
  const int blk = blockIdx.x;              // 0..511
  const int b   = blk >> 7;
  const int P0  = (blk & 127) * 128;
  const uint16_t* src = qf + (size_t)b*1048576;

  // Phase A: load view-tile [64 ch'][128 pos] u16 -> f32 LDS
  {
    const int r = t >> 2, q4 = t & 3;
    const uint16_t* rp = src + (size_t)r*16384 + P0 + q4*32;
#pragma unroll
    for(int i=0;i<4;i++){
      u32x4 raw = *(const u32x4*)(rp + i*8);     // 8 u16
#pragma unroll
      for(int j=0;j<4;j++){
        *(f32x2*)&tile[r][q4*32 + i*8 + j*2] = (f32x2){blo(raw[j]), bhi(raw[j])};
      }
    }
  }
  __syncthreads();

  // Phase B: LN per position -> swizzled bf16-pair A-tile
  {
    const int tx = t & 63, ty = t >> 6;
    const float sc = lsc[tx], bc = lbc[tx];
#pragma unroll
    for(int j=0;j<32;j++){
      int pr = ty + j*4;
      float v = tile[tx][pr];
      float s1 = wsum(v), s2 = wsum(v*v);
      float mu = s1*(1.f/64.f);
      float rs = rsqrtf(s2*(1.f/64.f) - mu*mu + 1e-5f);
      float cv = (v - mu)*rs*sc + bc;
      float va = __shfl(cv, (tx&31)*2), vb = __shfl(cv, (tx&31)*2+1);
      if(tx < 32)
        Acn[pr*32 + (tx ^ ((pr&7)<<2))] = ((uint32_t)f2bf(vb)<<16) | f2bf(va);
    }
  }
  __syncthreads();

  // Phase C: stage XQ tile (already swizzled content) into Axq (aliases tile)
  {
    const uint32_t* xsrc = XQ + (size_t)blk * 4096;
#pragma unroll
    for(int i=0;i<4;i++)
      *(u32x4*)&Axq[(i*256 + t)*4] = *(const u32x4*)&xsrc[(i*256 + t)*4];
  }
  __syncthreads();

  // Phase D: MFMA GEMMs. wave wv owns m-tiles {wv, wv+4}.
  const int wv = t >> 6, ln = t & 63;
  const size_t r0 = (size_t)blk * 128;

  // ---- Q = Axq @ wq * 0.125 ----
  {
    bf16x8 wf[4][2];
#pragma unroll
    for(int nt=0;nt<4;nt++)
#pragma unroll
      for(int ks=0;ks<2;ks++)
#pragma unroll
        for(int e=0;e<8;e++){
          int k = ks*32 + (ln>>4)*8 + e;
          wf[nt][ks][e] = (short)f2bf(wq[(size_t)k*64 + nt*16 + (ln&15)]);
        }
    f32x4 acc[2][4];
#pragma unroll
    for(int mi=0;mi<2;mi++)
#pragma unroll
      for(int nt=0;nt<4;nt++) acc[mi][nt] = (f32x4){0.f,0.f,0.f,0.f};
#pragma unroll
    for(int mi=0;mi<2;mi++){
      const int m = wv + mi*4;
      const int R = m*16 + (ln&15);
#pragma unroll
      for(int ks=0;ks<2;ks++){
        bf16x8 af = *(const bf16x8*)&Axq[R*32 + (((ks*4 + (ln>>4)) ^ (R&7))*4)];
#pragma unroll
        for(int nt=0;nt<4;nt++)
          acc[mi][nt] = __builtin_amdgcn_mfma_f32_16x16x32_bf16(af, wf[nt][ks], acc[mi][nt], 0,0,0);
      }
    }
#pragma unroll
    for(int mi=0;mi<2;mi++){
      const int m = wv + mi*4;
#pragma unroll
      for(int nt=0;nt<4;nt++){
        const int col = nt*16 + (ln&15);
#pragma unroll
        for(int r=0;r<4;r++){
          const size_t row = r0 + m*16 + (ln>>4)*4 + r;
          Qb[row*64 + col] = f2bf(acc[mi][nt][r]*0.125f);
        }
      }
    }
  }

  // ---- K|V = Acn @ wkv ----
  {
    bf16x8 wf[8][2];
#pragma unroll
    for(int nt=0;nt<8;nt++)
#pragma unroll
      for(int ks=0;ks<2;ks++)
#pragma unroll
        for(int e=0;e<8;e++){
          int k = ks*32 + (ln>>4)*8 + e;
          wf[nt][ks][e] = (short)f2bf(wkv[(size_t)k*128 + nt*16 + (ln&15)]);
        }
    f32x4 acc[2][8];
#pragma unroll
    for(int mi=0;mi<2;mi++)
#pragma unroll
      for(int nt=0;nt<8;nt++) acc[mi][nt] = (f32x4){0.f,0.f,0.f,0.f};
#pragma unroll
    for(int mi=0;mi<2;mi++){
      const int m = wv + mi*4;
      const int R = m*16 + (ln&15);
#pragma unroll
      for(int ks=0;ks<2;ks++){
        bf16x8 af = *(const bf16x8*)&Acn[R*32 + (((ks*4 + (ln>>4)) ^ (R&7))*4)];
#pragma unroll
        for(int nt=0;nt<8;nt++)
          acc[mi][nt] = __builtin_amdgcn_mfma_f32_16x16x32_bf16(af, wf[nt][ks], acc[mi][nt], 0,0,0);
      }
    }
#pragma unroll
    for(int mi=0;mi<2;mi++){
      const int m = wv + mi*4;
#pragma unroll
      for(int nt=0;nt<8;nt++){
        const int col = nt*16 + (ln&15);
#pragma unroll
        for(int r=0;r<4;r++){
          const size_t row = r0 + m*16 + (ln>>4)*4 + r;
          float v = acc[mi][nt][r];
          if(col < 64) Kb[row*64 + col]      = f2bf(v);
          else         Vb[row*64 + (col-64)] = f2bf(v);
        }
      }
    }
  }
}

// -------- K4: fused attention + out-projection. Block = one (b,h) grid row --------
__global__ __launch_bounds__(512) void k_attn_out(const uint16_t* __restrict__ Qb,
                                                  const uint16_t* __restrict__ Kb,
                                                  const uint16_t* __restrict__ Vb,
                                                  const float* __restrict__ wout,
                                                  const float* __restrict__ bout,
                                                  float* __restrict__ out){
  __shared__ uint32_t Ot[128*32];          // 16 KB swizzled O-tile
  const int t  = threadIdx.x;
  const int wv = t >> 6, ln = t & 63;
  const int blk = blockIdx.x;              // b*128 + h
  const int b = blk >> 7, h = blk & 127;
  const size_t base = (size_t)b * 16384;
  const size_t p0   = base + (size_t)h * 128;

  const int cl = ln & 15;
#pragma unroll
  for(int it=0; it<4; it++){
    const int local = wv*16 + it*4 + (ln>>4);   // = grid column w
    const size_t p = p0 + local;
    u32x2 qp = *(const u32x2*)((const char*)Qb + p*128 + cl*8);
    const float q0 = blo(qp.x), q1 = bhi(qp.x), q2 = blo(qp.y), q3 = bhi(qp.y);

    float sim[9];
    uint32_t v01[9], v23[9];
#pragma unroll
    for(int k=0;k<9;k++){
      int hh = min(max(h + k/3 - 1, 0), 127);
      int ww = min(max(local + k%3 - 1, 0), 127);
      size_t pos = base + hh*128 + ww;
      u32x2 kp = *(const u32x2*)((const char*)Kb + pos*128 + cl*8);
      u32x2 vp = *(const u32x2*)((const char*)Vb + pos*128 + cl*8);
      v01[k] = vp.x; v23[k] = vp.y;
      float s = q0*blo(kp.x) + q1*bhi(kp.x) + q2*blo(kp.y) + q3*bhi(kp.y);
#pragma unroll
      for(int o=8;o>0;o>>=1) s += __shfl_xor(s, o, 64);
      sim[k] = s;
    }
    float m = sim[0];
#pragma unroll
    for(int k=1;k<9;k++) m = fmaxf(m, sim[k]);
    float se = 0.f, o0 = 0.f, o1 = 0.f, o2 = 0.f, o3 = 0.f;
#pragma unroll
    for(int k=0;k<9;k++){
      float e = __expf(sim[k] - m);
      se += e;
      o0 += e*blo(v01[k]); o1 += e*bhi(v01[k]);
      o2 += e*blo(v23[k]); o3 += e*bhi(v23[k]);
    }
    float inv = 1.f/se;
    const uint32_t w01 = ((uint32_t)f2bf(o1*inv)<<16) | f2bf(o0*inv);
    const uint32_t w23 = ((uint32_t)f2bf(o3*inv)<<16) | f2bf(o2*inv);
    const int key = (local&7)<<2;
    Ot[local*32 + ((cl*2  ) ^ key)] = w01;
    Ot[local*32 + ((cl*2+1) ^ key)] = w23;
  }
  __syncthreads();

  // out-GEMM: wave wv -> m-tile wv (8 waves, 8 m-tiles of 16 rows)
  bf16x8 wf[4][2];
#pragma unroll
  for(int nt=0;nt<4;nt++)
#pragma unroll
    for(int ks=0;ks<2;ks++)
#pragma unroll
      for(int e=0;e<8;e++){
        int k = ks*32 + (ln>>4)*8 + e;
        wf[nt][ks][e] = (short)f2bf(wout[(size_t)k*64 + nt*16 + (ln&15)]);
      }
  f32x4 acc[4];
#pragma unroll
  for(int nt=0;nt<4;nt++) acc[nt] = (f32x4){0.f,0.f,0.f,0.f};
  const int R = wv*16 + (ln&15);
#pragma unroll
  for(int ks=0;ks<2;ks++){
    bf16x8 af = *(const bf16x8*)&Ot[R*32 + (((ks*4 + (ln>>4)) ^ (R&7))*4)];
#pragma unroll
    for(int nt=0;nt<4;nt++)
      acc[nt] = __builtin_amdgcn_mfma_f32_16x16x32_bf16(af, wf[nt][ks], acc[nt], 0,0,0);
  }
#pragma unroll
  for(int nt=0;nt<4;nt++){
    const int col = nt*16 + (ln&15);
    const float bb = bout[col];
#pragma unroll
    for(int r=0;r<4;r++){
      const size_t row = p0 + wv*16 + (ln>>4)*4 + r;
      out[row*89 + col] = acc[nt][r] + bb;
    }
  }
}

extern "C" void kernel_launch(void* const* d_in, const int* in_sizes, int n_in,
                              void* d_out, int out_size, void* d_ws, size_t ws_size,
                              hipStream_t stream){
  const float* image   = (const float*)d_in[0];
  const float* latents = (const float*)d_in[1];
  const float* coords  = (const float*)d_in[2];
  const float* lsq     = (const float*)d_in[3];
  const float* lbq     = (const float*)d_in[4];
  const float* lsc     = (const float*)d_in[5];
  const float* lbc     = (const float*)d_in[6];
  const float* wq      = (const float*)d_in[7];
  const float* wkv     = (const float*)d_in[8];
  const float* wout    = (const float*)d_in[9];
  const float* bout    = (const float*)d_in[10];
  float* out = (float*)d_out;

  // Workspace map (33.6 MB), regions reused as producers die:
  //   [0, 8.4M):      latT (K1->K2)   -> Kb (K3->K4)
  //   [8.4M, 16.8M):  Vb  (K3->K4)
  //   [16.8M, 25.2M): qf  (K2->K3)
  //   [25.2M, 33.6M): XQ  (K2->K3)    -> Qb (K3->K4, in-place per-block)
  char* ws = (char*)d_ws;
  uint16_t* latT = (uint16_t*)ws;
  uint16_t* Kb   = (uint16_t*)ws;
  uint16_t* Vb   = (uint16_t*)(ws + 8388608);
  uint16_t* qfB  = (uint16_t*)(ws + 16777216);
  uint32_t* XQ   = (uint32_t*)(ws + 25165824);
  uint16_t* Qb   = (uint16_t*)(ws + 25165824);

  dim3 trg(256, 4);
  k_tr_bf   <<<trg,   256, 0, stream>>>(latents, latT);
  k_sample  <<<16384, 256, 0, stream>>>(latT, coords, image, lsq, lbq, qfB, XQ, out);
  k_proj    <<<512,   256, 0, stream>>>(qfB, XQ, lsc, lbc, wq, wkv, Qb, Kb, Vb);
  k_attn_out<<<512,   512, 0, stream>>>(Qb, Kb, Vb, wout, bout, out);
}

// Round 9
// 145.248 us; speedup vs baseline: 4.2816x; 1.0926x over previous
//
#include <hip/hip_runtime.h>
#include <cstdint>

// B=4, C=64, H=W=128, N=16384 points/batch, 65536 total rows, out dim 89.

typedef __attribute__((ext_vector_type(8))) short bf16x8;
typedef __attribute__((ext_vector_type(4))) float f32x4;
typedef __attribute__((ext_vector_type(2))) float f32x2;
typedef __attribute__((ext_vector_type(4))) uint32_t u32x4;
typedef __attribute__((ext_vector_type(2))) uint32_t u32x2;

__device__ __forceinline__ float wsum(float v){
#pragma unroll
  for(int o=32;o>0;o>>=1) v += __shfl_xor(v,o,64);
  return v;
}
__device__ __forceinline__ unsigned short f2bf(float x){
  union{float f; uint32_t u;} c; c.f=x;
  uint32_t r = c.u + 0x7fffu + ((c.u>>16)&1u);   // RNE to bf16
  return (unsigned short)(r>>16);
}
__device__ __forceinline__ float bf2f(unsigned short h){
  union{uint32_t u; float f;} c; c.u = ((uint32_t)h)<<16; return c.f;
}
__device__ __forceinline__ float blo(uint32_t u){
  union{uint32_t x; float f;} c; c.x = u<<16; return c.f;
}
__device__ __forceinline__ float bhi(uint32_t u){
  union{uint32_t x; float f;} c; c.x = u & 0xffff0000u; return c.f;
}

// -------- K1: latents [C][HW] -> lat_t [HW][C] (fp32 -> bf16 transpose) --------
__global__ __launch_bounds__(256) void k_tr_bf(const float* __restrict__ in,
                                               uint16_t* __restrict__ out){
  __shared__ float t[64][65];
  const int b  = blockIdx.y;
  const int p0 = blockIdx.x * 64;
  const float* src = in  + (size_t)b * (64 * 16384);
  uint16_t*    dst = out + (size_t)b * (64 * 16384);
  const int tx = threadIdx.x & 63, ty = threadIdx.x >> 6;
#pragma unroll
  for(int j=0;j<16;j++){ int r = ty + j*4; t[r][tx] = src[(size_t)r*16384 + p0 + tx]; }
  __syncthreads();
#pragma unroll
  for(int j=0;j<16;j++){ int pr = ty + j*4; dst[(size_t)(p0+pr)*64 + tx] = f2bf(t[tx][pr]); }
}

// -------- K2: bilinear sample + extras + LN(q) -> XQ. 16 lanes/point, 4 ch/lane --------
__global__ __launch_bounds__(256) void k_sample(const uint16_t* __restrict__ lat_t,
                                                const float* __restrict__ coords,
                                                const float* __restrict__ image,
                                                const float* __restrict__ lsq,
                                                const float* __restrict__ lbq,
                                                uint16_t* __restrict__ qf,
                                                uint32_t* __restrict__ xq,
                                                float* __restrict__ out){
  const int t  = threadIdx.x;
  const int ln = t & 63;
  const int cl = ln & 15;                          // channels 4cl..4cl+3
  const int pidx = blockIdx.x*16 + (t>>6)*4 + (ln>>4);
  const int b = pidx >> 14;
  const float y = coords[(size_t)pidx*2 + 0];
  const float x = coords[(size_t)pidx*2 + 1];

  // ---- latents bilinear (128x128), zeros padding ----
  float ix = ((x + 1.f)*128.f - 1.f)*0.5f;
  float iy = ((y + 1.f)*128.f - 1.f)*0.5f;
  float x0 = floorf(ix), y0 = floorf(iy);
  float wx1 = ix - x0, wy1 = iy - y0;
  float a0=0.f, a1=0.f, a2=0.f, a3=0.f, qcy=0.f, qcx=0.f;
  const char* latb = (const char*)(lat_t + (size_t)b*16384*64);
#pragma unroll
  for(int cy=0; cy<2; cy++){
#pragma unroll
    for(int cx=0; cx<2; cx++){
      int xi = (int)x0 + cx, yi = (int)y0 + cy;
      float w = (cx ? wx1 : 1.f-wx1) * (cy ? wy1 : 1.f-wy1);
      bool valid = (xi>=0)&&(xi<128)&&(yi>=0)&&(yi<128);
      float wv = valid ? w : 0.f;
      int xc = min(max(xi,0),127), yc = min(max(yi,0),127);
      u32x2 kp = *(const u32x2*)(latb + (size_t)(yc*128 + xc)*128 + cl*8);
      a0 += wv*blo(kp.x); a1 += wv*bhi(kp.x);
      a2 += wv*blo(kp.y); a3 += wv*bhi(kp.y);
      qcy += wv * (-1.f + (2.f*(float)yc + 1.f)*(1.f/128.f));
      qcx += wv * (-1.f + (2.f*(float)xc + 1.f)*(1.f/128.f));
    }
  }
  // qf row write (bf16 x4 = 8B/lane)
  {
    u32x2 qw;
    qw.x = ((uint32_t)f2bf(a1)<<16) | f2bf(a0);
    qw.y = ((uint32_t)f2bf(a3)<<16) | f2bf(a2);
    *(u32x2*)((char*)qf + (size_t)pidx*128 + cl*8) = qw;
  }

  // ---- LN(q): 16-lane group reduce (4 ch in-lane) ----
  float s1 = (a0+a1)+(a2+a3);
  float s2 = (a0*a0+a1*a1)+(a2*a2+a3*a3);
#pragma unroll
  for(int o=8;o>0;o>>=1){ s1 += __shfl_xor(s1,o,64); s2 += __shfl_xor(s2,o,64); }
  float mu = s1*(1.f/64.f);
  float rs = rsqrtf(s2*(1.f/64.f) - mu*mu + 1e-5f);
  f32x4 sc4 = *(const f32x4*)&lsq[cl*4];
  f32x4 bb4 = *(const f32x4*)&lbq[cl*4];
  float x0v = (a0-mu)*rs*sc4[0] + bb4[0];
  float x1v = (a1-mu)*rs*sc4[1] + bb4[1];
  float x2v = (a2-mu)*rs*sc4[2] + bb4[2];
  float x3v = (a3-mu)*rs*sc4[3] + bb4[3];
  // XQ swizzled write: word u holds channels 2u,2u+1; key = (row&7)<<2
  {
    const int key = (pidx&7)<<2;
    xq[(size_t)pidx*32 + ((cl*2  ) ^ key)] = ((uint32_t)f2bf(x1v)<<16) | f2bf(x0v);
    xq[(size_t)pidx*32 + ((cl*2+1) ^ key)] = ((uint32_t)f2bf(x3v)<<16) | f2bf(x2v);
  }

  // ---- image sample (256x256, C=1) ----
  float jx = ((x + 1.f)*256.f - 1.f)*0.5f;
  float jy = ((y + 1.f)*256.f - 1.f)*0.5f;
  float jx0 = floorf(jx), jy0 = floorf(jy);
  float ux1 = jx - jx0, uy1 = jy - jy0;
  float acc2 = 0.f;
  const float* imb = image + (size_t)b*256*256;
#pragma unroll
  for(int cy=0; cy<2; cy++){
#pragma unroll
    for(int cx=0; cx<2; cx++){
      int xi = (int)jx0 + cx, yi = (int)jy0 + cy;
      float w = (cx ? ux1 : 1.f-ux1) * (cy ? uy1 : 1.f-uy1);
      bool valid = (xi>=0)&&(xi<256)&&(yi>=0)&&(yi<256);
      int xc = min(max(xi,0),255), yc = min(max(yi,0),255);
      acc2 += (valid ? w : 0.f) * imb[yc*256 + xc];
    }
  }
  size_t obase = (size_t)pidx * 89;
  if(cl == 0) out[obase + 64] = acc2;

  // ---- positional encoding: out[65..88], idx = cl + 16j ----
#pragma unroll
  for(int j=0;j<2;j++){
    int idx = cl + j*16;
    if(idx < 24){
      int r = (idx < 12) ? idx : idx - 12;
      int d = r / 6, o = r % 6;
      float cval = (d == 0) ? qcy : qcx;
      cval = (cval + 1.f) * 0.5f;
      float arg = cval * 3.14159265358979323846f * (float)(1 << o);
      out[obase + 65 + idx] = (idx < 12) ? sinf(arg) : cosf(arg);
    }
  }
}

// -------- K3: fused {view-transpose + LN_c + KV-GEMM} + {Q-GEMM} --------
// One block = 128 consecutive positions of one batch. 256 threads (4 waves).
__global__ __launch_bounds__(256) void k_proj(const uint16_t* __restrict__ qf,
                                              const uint32_t* __restrict__ XQ,
                                              const float* __restrict__ lsc,
                                              const float* __restrict__ lbc,
                                              const float* __restrict__ wq,
                                              const float* __restrict__ wkv,
                                              uint16_t* __restrict__ Qb,
                                              uint16_t* __restrict__ Kb,
                                              uint16_t* __restrict__ Vb){
  __shared__ float tile[64][130];          // 33.3 KB
  __shared__ uint32_t Acn[128*32];         // 16 KB swizzled A (context LN)
  uint32_t* Axq = (uint32_t*)&tile[0][0];  // aliases tile after phase B

  const int t   = threadIdx.x;
  const int blk = blockIdx.x;              // 0..511
  const int b   = blk >> 7;
  const int P0  = (blk & 127) * 128;
  const uint16_t* src = qf + (size_t)b*1048576;

  // Phase A: load view-tile [64 ch'][128 pos] u16 -> f32 LDS
  {
    const int r = t >> 2, q4 = t & 3;
    const uint16_t* rp = src + (size_t)r*16384 + P0 + q4*32;
#pragma unroll
    for(int i=0;i<4;i++){
      u32x4 raw = *(const u32x4*)(rp + i*8);     // 8 u16
#pragma unroll
      for(int j=0;j<4;j++){
        *(f32x2*)&tile[r][q4*32 + i*8 + j*2] = (f32x2){blo(raw[j]), bhi(raw[j])};
      }
    }
  }
  __syncthreads();

  // Phase B: LN per position -> swizzled bf16-pair A-tile
  {
    const int tx = t & 63, ty = t >> 6;
    const float sc = lsc[tx], bc = lbc[tx];
#pragma unroll
    for(int j=0;j<32;j++){
      int pr = ty + j*4;
      float v = tile[tx][pr];
      float s1 = wsum(v), s2 = wsum(v*v);
      float mu = s1*(1.f/64.f);
      float rs = rsqrtf(s2*(1.f/64.f) - mu*mu + 1e-5f);
      float cv = (v - mu)*rs*sc + bc;
      float va = __shfl(cv, (tx&31)*2), vb = __shfl(cv, (tx&31)*2+1);
      if(tx < 32)
        Acn[pr*32 + (tx ^ ((pr&7)<<2))] = ((uint32_t)f2bf(vb)<<16) | f2bf(va);
    }
  }
  __syncthreads();

  // Phase C: stage XQ tile (already swizzled content) into Axq (aliases tile)
  {
    const uint32_t* xsrc = XQ + (size_t)blk * 4096;
#pragma unroll
    for(int i=0;i<4;i++)
      *(u32x4*)&Axq[(i*256 + t)*4] = *(const u32x4*)&xsrc[(i*256 + t)*4];
  }
  __syncthreads();

  // Phase D: MFMA GEMMs. wave wv owns m-tiles {wv, wv+4}.
  const int wv = t >> 6, ln = t & 63;
  const size_t r0 = (size_t)blk * 128;

  // ---- Q = Axq @ wq * 0.125 ----
  {
    bf16x8 wf[4][2];
#pragma unroll
    for(int nt=0;nt<4;nt++)
#pragma unroll
      for(int ks=0;ks<2;ks++)
#pragma unroll
        for(int e=0;e<8;e++){
          int k = ks*32 + (ln>>4)*8 + e;
          wf[nt][ks][e] = (short)f2bf(wq[(size_t)k*64 + nt*16 + (ln&15)]);
        }
    f32x4 acc[2][4];
#pragma unroll
    for(int mi=0;mi<2;mi++)
#pragma unroll
      for(int nt=0;nt<4;nt++) acc[mi][nt] = (f32x4){0.f,0.f,0.f,0.f};
#pragma unroll
    for(int mi=0;mi<2;mi++){
      const int m = wv + mi*4;
      const int R = m*16 + (ln&15);
#pragma unroll
      for(int ks=0;ks<2;ks++){
        bf16x8 af = *(const bf16x8*)&Axq[R*32 + (((ks*4 + (ln>>4)) ^ (R&7))*4)];
#pragma unroll
        for(int nt=0;nt<4;nt++)
          acc[mi][nt] = __builtin_amdgcn_mfma_f32_16x16x32_bf16(af, wf[nt][ks], acc[mi][nt], 0,0,0);
      }
    }
#pragma unroll
    for(int mi=0;mi<2;mi++){
      const int m = wv + mi*4;
#pragma unroll
      for(int nt=0;nt<4;nt++){
        const int col = nt*16 + (ln&15);
#pragma unroll
        for(int r=0;r<4;r++){
          const size_t row = r0 + m*16 + (ln>>4)*4 + r;
          Qb[row*64 + col] = f2bf(acc[mi][nt][r]*0.125f);
        }
      }
    }
  }

  // ---- K|V = Acn @ wkv ----
  {
    bf16x8 wf[8][2];
#pragma unroll
    for(int nt=0;nt<8;nt++)
#pragma unroll
      for(int ks=0;ks<2;ks++)
#pragma unroll
        for(int e=0;e<8;e++){
          int k = ks*32 + (ln>>4)*8 + e;
          wf[nt][ks][e] = (short)f2bf(wkv[(size_t)k*128 + nt*16 + (ln&15)]);
        }
    f32x4 acc[2][8];
#pragma unroll
    for(int mi=0;mi<2;mi++)
#pragma unroll
      for(int nt=0;nt<8;nt++) acc[mi][nt] = (f32x4){0.f,0.f,0.f,0.f};
#pragma unroll
    for(int mi=0;mi<2;mi++){
      const int m = wv + mi*4;
      const int R = m*16 + (ln&15);
#pragma unroll
      for(int ks=0;ks<2;ks++){
        bf16x8 af = *(const bf16x8*)&Acn[R*32 + (((ks*4 + (ln>>4)) ^ (R&7))*4)];
#pragma unroll
        for(int nt=0;nt<8;nt++)
          acc[mi][nt] = __builtin_amdgcn_mfma_f32_16x16x32_bf16(af, wf[nt][ks], acc[mi][nt], 0,0,0);
      }
    }
#pragma unroll
    for(int mi=0;mi<2;mi++){
      const int m = wv + mi*4;
#pragma unroll
      for(int nt=0;nt<8;nt++){
        const int col = nt*16 + (ln&15);
#pragma unroll
        for(int r=0;r<4;r++){
          const size_t row = r0 + m*16 + (ln>>4)*4 + r;
          float v = acc[mi][nt][r];
          if(col < 64) Kb[row*64 + col]      = f2bf(v);
          else         Vb[row*64 + (col-64)] = f2bf(v);
        }
      }
    }
  }
}

// -------- K4: fused attention + out-projection. Block = one (b,h) grid row --------
__global__ __launch_bounds__(512) void k_attn_out(const uint16_t* __restrict__ Qb,
                                                  const uint16_t* __restrict__ Kb,
                                                  const uint16_t* __restrict__ Vb,
                                                  const float* __restrict__ wout,
                                                  const float* __restrict__ bout,
                                                  float* __restrict__ out){
  __shared__ uint32_t Ot[128*32];          // 16 KB swizzled O-tile
  const int t  = threadIdx.x;
  const int wv = t >> 6, ln = t & 63;
  const int blk = blockIdx.x;              // b*128 + h
  const int b = blk >> 7, h = blk & 127;
  const size_t base = (size_t)b * 16384;
  const size_t p0   = base + (size_t)h * 128;

  const int cl = ln & 15;
#pragma unroll
  for(int it=0; it<4; it++){
    const int local = wv*16 + it*4 + (ln>>4);   // = grid column w
    const size_t p = p0 + local;
    u32x2 qp = *(const u32x2*)((const char*)Qb + p*128 + cl*8);
    const float q0 = blo(qp.x), q1 = bhi(qp.x), q2 = blo(qp.y), q3 = bhi(qp.y);

    float sim[9];
    uint32_t v01[9], v23[9];
#pragma unroll
    for(int k=0;k<9;k++){
      int hh = min(max(h + k/3 - 1, 0), 127);
      int ww = min(max(local + k%3 - 1, 0), 127);
      size_t pos = base + hh*128 + ww;
      u32x2 kp = *(const u32x2*)((const char*)Kb + pos*128 + cl*8);
      u32x2 vp = *(const u32x2*)((const char*)Vb + pos*128 + cl*8);
      v01[k] = vp.x; v23[k] = vp.y;
      float s = q0*blo(kp.x) + q1*bhi(kp.x) + q2*blo(kp.y) + q3*bhi(kp.y);
#pragma unroll
      for(int o=8;o>0;o>>=1) s += __shfl_xor(s, o, 64);
      sim[k] = s;
    }
    float m = sim[0];
#pragma unroll
    for(int k=1;k<9;k++) m = fmaxf(m, sim[k]);
    float se = 0.f, o0 = 0.f, o1 = 0.f, o2 = 0.f, o3 = 0.f;
#pragma unroll
    for(int k=0;k<9;k++){
      float e = __expf(sim[k] - m);
      se += e;
      o0 += e*blo(v01[k]); o1 += e*bhi(v01[k]);
      o2 += e*blo(v23[k]); o3 += e*bhi(v23[k]);
    }
    float inv = 1.f/se;
    const uint32_t w01 = ((uint32_t)f2bf(o1*inv)<<16) | f2bf(o0*inv);
    const uint32_t w23 = ((uint32_t)f2bf(o3*inv)<<16) | f2bf(o2*inv);
    const int key = (local&7)<<2;
    Ot[local*32 + ((cl*2  ) ^ key)] = w01;
    Ot[local*32 + ((cl*2+1) ^ key)] = w23;
  }
  __syncthreads();

  // out-GEMM: wave wv -> m-tile wv (8 waves, 8 m-tiles of 16 rows)
  bf16x8 wf[4][2];
#pragma unroll
  for(int nt=0;nt<4;nt++)
#pragma unroll
    for(int ks=0;ks<2;ks++)
#pragma unroll
      for(int e=0;e<8;e++){
        int k = ks*32 + (ln>>4)*8 + e;
        wf[nt][ks][e] = (short)f2bf(wout[(size_t)k*64 + nt*16 + (ln&15)]);
      }
  f32x4 acc[4];
#pragma unroll
  for(int nt=0;nt<4;nt++) acc[nt] = (f32x4){0.f,0.f,0.f,0.f};
  const int R = wv*16 + (ln&15);
#pragma unroll
  for(int ks=0;ks<2;ks++){
    bf16x8 af = *(const bf16x8*)&Ot[R*32 + (((ks*4 + (ln>>4)) ^ (R&7))*4)];
#pragma unroll
    for(int nt=0;nt<4;nt++)
      acc[nt] = __builtin_amdgcn_mfma_f32_16x16x32_bf16(af, wf[nt][ks], acc[nt], 0,0,0);
  }
#pragma unroll
  for(int nt=0;nt<4;nt++){
    const int col = nt*16 + (ln&15);
    const float bb = bout[col];
#pragma unroll
    for(int r=0;r<4;r++){
      const size_t row = p0 + wv*16 + (ln>>4)*4 + r;
      out[row*89 + col] = acc[nt][r] + bb;
    }
  }
}

extern "C" void kernel_launch(void* const* d_in, const int* in_sizes, int n_in,
                              void* d_out, int out_size, void* d_ws, size_t ws_size,
                              hipStream_t stream){
  const float* image   = (const float*)d_in[0];
  const float* latents = (const float*)d_in[1];
  const float* coords  = (const float*)d_in[2];
  const float* lsq     = (const float*)d_in[3];
  const float* lbq     = (const float*)d_in[4];
  const float* lsc     = (const float*)d_in[5];
  const float* lbc     = (const float*)d_in[6];
  const float* wq      = (const float*)d_in[7];
  const float* wkv     = (const float*)d_in[8];
  const float* wout    = (const float*)d_in[9];
  const float* bout    = (const float*)d_in[10];
  float* out = (float*)d_out;

  // Workspace map (33.6 MB), regions reused as producers die:
  //   [0, 8.4M):      latT (K1->K2)   -> Kb (K3->K4)
  //   [8.4M, 16.8M):  Vb  (K3->K4)
  //   [16.8M, 25.2M): qf  (K2->K3)
  //   [25.2M, 33.6M): XQ  (K2->K3)    -> Qb (K3->K4, in-place per-block)
  char* ws = (char*)d_ws;
  uint16_t* latT = (uint16_t*)ws;
  uint16_t* Kb   = (uint16_t*)ws;
  uint16_t* Vb   = (uint16_t*)(ws + 8388608);
  uint16_t* qfB  = (uint16_t*)(ws + 16777216);
  uint32_t* XQ   = (uint32_t*)(ws + 25165824);
  uint16_t* Qb   = (uint16_t*)(ws + 25165824);

  dim3 trg(256, 4);
  k_tr_bf   <<<trg,   256, 0, stream>>>(latents, latT);
  k_sample  <<<4096,  256, 0, stream>>>(latT, coords, image, lsq, lbq, qfB, XQ, out);
  k_proj    <<<512,   256, 0, stream>>>(qfB, XQ, lsc, lbc, wq, wkv, Qb, Kb, Vb);
  k_attn_out<<<512,   512, 0, stream>>>(Qb, Kb, Vb, wout, bout, out);
}